// Round 15
// baseline (320.866 us; speedup 1.0000x reference)
//
#include <hip/hip_runtime.h>
#include <hip/hip_cooperative_groups.h>

namespace cg = cooperative_groups;

// GCN 2-layer + mean-pool + readout.
// Algebra: aggregation is linear, so transform FIRST:
//   Y      = (norm_out ⊙ X) @ W1            (dense register-tiled GEMM, fp32)
//   h1[n]  = relu( norm_in[n] * sum_{e:dst=n} Y[src_e] + b1 )
//   out    = ((1/N) * sum_u c[u]*h1[u]) @ W2 + b2  @ Wr^T + br
//   c[u]   = norm_out[u] * sum_{e:src=u} norm_in[dst_e]
//
// k_agg roofline (r9-r13): gathered volume 800K edges x 96 cols x 4B = 307MB
// = 19.2M 16B-sectors, invariant across geometries; L2 serves ~16.8
// sectors/cy/XCD -> ~60us wall. fp16 ruled out by accuracy. PARKED.
//
// Round-15 change: the three preproc kernels (part/hist/place_bin) fuse into
// ONE cooperative kernel k_pre with grid.sync() between phases — cross-round
// accounting shows ~4-6us overhead per small dispatch; 8 -> 6 dispatches.
// Per-bucket scan result is carried in a REGISTER across the grid sync.
//
// Pipeline: memset(26KB) -> k_pre(coop,392) -> k_xform -> k_agg -> k_final.

constexpr int NN = 50000;
constexpr int NE = 800000;
constexpr int NB = 196;         // buckets of 256 nodes
constexpr int CAP = 6144;       // bucket capacity (mean 4082, +32 sigma)
constexpr int NCHUNK = (NE + 2047) / 2048;   // 391 partition chunks
constexpr int GRID_PRE = 2 * NB;             // 392 blocks

// ws layout in 4-byte units:
constexpr int OFF_SVEC     = 0;        // float[256]  (zeroed)
constexpr int OFF_BCURD    = 256;      // int[196*16] line-padded (zeroed)
constexpr int OFF_BCURS    = 3392;     // int[196*16] line-padded (zeroed)
constexpr int OFF_NORM_OUT = 6528;     // float[50000]
constexpr int OFF_NORM_IN  = 56528;    // float[50000]
constexpr int OFF_CW       = 106528;   // float[50000]
constexpr int OFF_ROW_PTR  = 156528;   // int[50001] -> pad 206532
constexpr int OFF_EDGE_SRC = 206532;   // ushort[800000] = 400000 ints -> 606532
constexpr int OFF_PD       = 606532;   // int[196*6144] (dead after k_pre)
constexpr int OFF_PS       = 1810756;  // int[196*6144] (dead after k_pre)
constexpr int OFF_YP       = 606532;   // float[8][50000][12] aliases PD+PS
                                       // end 5406532 words = 21.6MB
constexpr size_t ZERO_BYTES = (size_t)(OFF_NORM_OUT) * 4;   // svec + cursors

// Fused preproc (cooperative, 392 blocks):
//   Phase A (blocks 0..390): dual partition by dst/src bucket with LDS
//     reorder-then-flush (coalesced bucket-run writes).
//   Phase B (blocks 0..195): per-bucket hist -> base reduce -> 256-scan ->
//     row_ptr + norm_in. Scan result kept in a register for phase C.
//   Phase C: blocks 0..195 place edges into CSR (ushort edge_src);
//     blocks 196..391 do out-degree + c_raw -> norm_out, cw.
__global__ __launch_bounds__(256)
void k_pre(const int* __restrict__ src, const int* __restrict__ dst,
           int* __restrict__ bcur_d, int* __restrict__ bcur_s,
           int* __restrict__ pd, int* __restrict__ ps,
           int* __restrict__ row_ptr, float* __restrict__ norm_in,
           unsigned short* __restrict__ edge_src,
           float* __restrict__ norm_out, float* __restrict__ cw) {
  cg::grid_group grid = cg::this_grid();
  __shared__ int hd[256], hs[256], gd[256], gs[256];
  __shared__ int ldx[256], cur[256], scn[256];
  __shared__ int stage[2048];
  __shared__ unsigned char stageB[2048];
  __shared__ float fbuf[256];
  const int t = threadIdx.x;
  const int bid = blockIdx.x;

  // ===== Phase A: dual partition =====
  if (bid < NCHUNK) {
    hd[t] = 0; hs[t] = 0;
    __syncthreads();
    const int e0 = bid * 2048;
    int s_[8], d_[8];
#pragma unroll
    for (int i = 0; i < 8; ++i) {
      int e = e0 + i * 256 + t;
      bool v = e < NE;
      s_[i] = v ? src[e] : -1;
      d_[i] = v ? dst[e] : -1;
      if (v) { atomicAdd(&hd[d_[i] >> 8], 1); atomicAdd(&hs[s_[i] >> 8], 1); }
    }
    __syncthreads();
    if (t < NB) {
      int c = hd[t];
      gd[t] = c ? (t * CAP + atomicAdd(&bcur_d[t * 16], c)) : 0;
      c = hs[t];
      gs[t] = c ? (t * CAP + atomicAdd(&bcur_s[t * 16], c)) : 0;
    }

    // dst partition: scan -> LDS place -> linear flush
    scn[t] = hd[t];
    __syncthreads();
    for (int off = 1; off < 256; off <<= 1) {
      int u = (t >= off) ? scn[t - off] : 0;
      __syncthreads();
      scn[t] += u;
      __syncthreads();
    }
    ldx[t] = scn[t] - hd[t];
    cur[t] = scn[t] - hd[t];
    const int totd = scn[255];
    __syncthreads();
#pragma unroll
    for (int i = 0; i < 8; ++i) {
      if (d_[i] >= 0) {
        int B = d_[i] >> 8;
        int p = atomicAdd(&cur[B], 1);             // LDS
        stage[p] = (s_[i] << 8) | (d_[i] & 255);
        stageB[p] = (unsigned char)B;
      }
    }
    __syncthreads();
    for (int j = t; j < totd; j += 256) {          // coalesced within runs
      int B = stageB[j];
      pd[gd[B] + (j - ldx[B])] = stage[j];
    }
    __syncthreads();

    // src partition: same machinery, reusing stage
    scn[t] = hs[t];
    __syncthreads();
    for (int off = 1; off < 256; off <<= 1) {
      int u = (t >= off) ? scn[t - off] : 0;
      __syncthreads();
      scn[t] += u;
      __syncthreads();
    }
    ldx[t] = scn[t] - hs[t];
    cur[t] = scn[t] - hs[t];
    const int tots = scn[255];
    __syncthreads();
#pragma unroll
    for (int i = 0; i < 8; ++i) {
      if (s_[i] >= 0) {
        int B = s_[i] >> 8;
        int p = atomicAdd(&cur[B], 1);             // LDS
        stage[p] = (d_[i] << 8) | (s_[i] & 255);
        stageB[p] = (unsigned char)B;
      }
    }
    __syncthreads();
    for (int j = t; j < tots; j += 256) {
      int B = stageB[j];
      ps[gs[B] + (j - ldx[B])] = stage[j];
    }
  }
  grid.sync();

  // ===== Phase B: per-bucket hist -> row_ptr + norm_in =====
  int my_excl = 0;                                 // carried to phase C
  if (bid < NB) {
    hd[t] = 0;
    __syncthreads();
    const int cnt = bcur_d[bid * 16];
    const int* pe = pd + bid * CAP;
    for (int i = t; i < cnt; i += 256) atomicAdd(&hd[pe[i] & 255], 1);

    scn[t] = (t < bid) ? bcur_d[t * 16] : 0;       // bucket base reduce
    __syncthreads();
    for (int s = 128; s > 0; s >>= 1) {
      if (t < s) scn[t] += scn[t + s];
      __syncthreads();
    }
    const int base0 = scn[0];
    __syncthreads();

    int h = hd[t];
    scn[t] = h;
    __syncthreads();
    for (int off = 1; off < 256; off <<= 1) {
      int u = (t >= off) ? scn[t - off] : 0;
      __syncthreads();
      scn[t] += u;
      __syncthreads();
    }
    my_excl = base0 + scn[t] - h;
    int n = bid * 256 + t;
    if (n < NN) {
      row_ptr[n] = my_excl;
      norm_in[n] = 1.0f / sqrtf((float)max(h, 1));
    }
    if (bid == NB - 1 && t == 0) row_ptr[NN] = base0 + cnt;
  }
  grid.sync();

  // ===== Phase C: placement (0..195) / bin_src (196..391) =====
  if (bid < NB) {
    cur[t] = my_excl;                              // register-carried cursor
    __syncthreads();
    const int cnt = bcur_d[bid * 16];
    const int* pe = pd + bid * CAP;
    for (int i = t; i < cnt; i += 256) {
      int p = pe[i];
      int pos = atomicAdd(&cur[p & 255], 1);       // LDS
      edge_src[pos] = (unsigned short)(p >> 8);
    }
  } else if (bid < 2 * NB) {
    const int b = bid - NB;
    cur[t] = 0; fbuf[t] = 0.f;
    __syncthreads();
    const int cnt = bcur_s[b * 16];
    const int* pe = ps + b * CAP;
    for (int i = t; i < cnt; i += 256) {
      int p = pe[i];
      atomicAdd(&cur[p & 255], 1);                 // LDS
      atomicAdd(&fbuf[p & 255], norm_in[p >> 8]);  // LDS float add
    }
    __syncthreads();
    int n = b * 256 + t;
    if (n < NN) {
      float no = 1.0f / sqrtf((float)max(cur[t], 1));
      norm_out[n] = no;
      cw[n] = no * fbuf[t];
    }
  }
}

// Y = (norm_out ⊙ X) @ W1 — register-tiled GEMM, 8x12-col panel output.
// W1 staged in LDS in 32-row chunks (12.3KB): W1 (36.9KB) > L1 (32KB) was
// thrashing ~940MB through L2. FMA order unchanged -> bitwise-same Y.
__global__ __launch_bounds__(256, 4)
void k_xform(const float* __restrict__ feats, const float* __restrict__ norm_out,
             const float* __restrict__ W1, float* __restrict__ YP) {
  __shared__ float XT[96][68];            // [k][node], pad 64->68 (26.1KB)
  __shared__ float W1c[32][96];           // one 32-row chunk of W1 (12.3KB)
  const int t = threadIdx.x;
  const int nb = blockIdx.x * 64;         // tile base node

  const float4* f4 = (const float4*)feats;
#pragma unroll
  for (int i = 0; i < 6; ++i) {           // 6*256 = 1536 float4 = 64x96 floats
    int idx4 = i * 256 + t;
    int n = idx4 / 24;
    int kq = idx4 % 24;
    int ng = nb + n;
    float4 v = make_float4(0.f, 0.f, 0.f, 0.f);
    float no = 0.f;
    if (ng < NN) { v = f4[(size_t)ng * 24 + kq]; no = norm_out[ng]; }
    XT[kq * 4 + 0][n] = v.x * no;
    XT[kq * 4 + 1][n] = v.y * no;
    XT[kq * 4 + 2][n] = v.z * no;
    XT[kq * 4 + 3][n] = v.w * no;
  }
  __syncthreads();

  const int tn = t & 7;                   // panel / column chunk: cols 12*tn..
  const int tm = t >> 3;                  // node pair: nodes 2*tm, 2*tm+1
  float acc0[12], acc1[12];
#pragma unroll
  for (int c = 0; c < 12; ++c) { acc0[c] = 0.f; acc1[c] = 0.f; }

  for (int kb = 0; kb < 3; ++kb) {
    const float4* Wg = (const float4*)(W1 + kb * 32 * 96);
#pragma unroll
    for (int i = 0; i < 3; ++i) {
      int j = i * 256 + t;
      *(float4*)&W1c[j / 24][(j % 24) * 4] = Wg[j];
    }
    __syncthreads();
#pragma unroll
    for (int kk = 0; kk < 32; ++kk) {
      int k = kb * 32 + kk;
      float2 x = *(const float2*)&XT[k][2 * tm];
      float4 w0 = *(const float4*)&W1c[kk][12 * tn];
      float4 w1 = *(const float4*)&W1c[kk][12 * tn + 4];
      float4 w2 = *(const float4*)&W1c[kk][12 * tn + 8];
      const float w[12] = {w0.x, w0.y, w0.z, w0.w, w1.x, w1.y, w1.z, w1.w,
                           w2.x, w2.y, w2.z, w2.w};
#pragma unroll
      for (int c = 0; c < 12; ++c) {
        acc0[c] = fmaf(x.x, w[c], acc0[c]);
        acc1[c] = fmaf(x.y, w[c], acc1[c]);
      }
    }
    __syncthreads();
  }

  int n0 = nb + 2 * tm;
  if (n0 < NN) {
    float4* yp = (float4*)(YP + ((size_t)tn * NN + n0) * 12);
    yp[0] = make_float4(acc0[0], acc0[1], acc0[2], acc0[3]);
    yp[1] = make_float4(acc0[4], acc0[5], acc0[6], acc0[7]);
    yp[2] = make_float4(acc0[8], acc0[9], acc0[10], acc0[11]);
  }
  if (n0 + 1 < NN) {
    float4* yp = (float4*)(YP + ((size_t)tn * NN + n0 + 1) * 12);
    yp[0] = make_float4(acc1[0], acc1[1], acc1[2], acc1[3]);
    yp[1] = make_float4(acc1[4], acc1[5], acc1[6], acc1[7]);
    yp[2] = make_float4(acc1[8], acc1[9], acc1[10], acc1[11]);
  }
}

// Panel-per-XCD CSR gather with node-pair ILP (the ~60us L2-volume wall).
__global__ __launch_bounds__(256, 6)
void k_agg(const float* __restrict__ YP,
           const float* __restrict__ norm_in, const float* __restrict__ cw,
           const int* __restrict__ row_ptr, const unsigned short* __restrict__ edge_src,
           const float* __restrict__ b1, float* __restrict__ svec) {
  __shared__ float red[12];
  const int tid = threadIdx.x;
  if (tid < 12) red[tid] = 0.f;
  __syncthreads();

  const int panel = blockIdx.x & 7;
  const int bp    = blockIdx.x >> 3;
  const int g = tid >> 5, l = tid & 31;
  const int ei = l / 3;
  const int q4 = (l - 3 * ei) * 4;          // element offset of this lane's quad
  const bool act = (l < 24);

  const float* Yp = YP + (size_t)panel * NN * 12;
  float4 b4 = make_float4(0.f, 0.f, 0.f, 0.f);
  if (l < 3) b4 = ((const float4*)b1)[3 * panel + l];

  float a0 = 0.f, a1 = 0.f, a2 = 0.f, a3 = 0.f;

  const int gid = bp * 8 + g;
  for (int n = gid; n < NN; n += 4096) {
    const int m = n + 2048;
    const bool hb = (m < NN);
    int e1a = row_ptr[n + 1], basea = row_ptr[n];
    int e1b = 0, baseb = 0;
    if (hb) { e1b = row_ptr[m + 1]; baseb = row_ptr[m]; }
    float va0 = 0.f, va1 = 0.f, va2 = 0.f, va3 = 0.f;
    float vb0 = 0.f, vb1 = 0.f, vb2 = 0.f, vb3 = 0.f;

    while (basea < e1a || baseb < e1b) {
      int cnta = min(32, e1a - basea);
      int cntb = min(32, e1b - baseb);
      int esa = 0, esb = 0;
      if (basea + l < e1a) esa = edge_src[basea + l] * 12;
      if (baseb + l < e1b) esb = edge_src[baseb + l] * 12;

      if (cnta > 0) {
        int s0 = __shfl(esa, ei, 32);
        float4 f0 = make_float4(0.f, 0.f, 0.f, 0.f);
        if (act && ei < cnta) f0 = *(const float4*)(Yp + s0 + q4);
        if (cnta > 8) {
          int s1 = __shfl(esa, 8 + ei, 32);
          float4 f1 = make_float4(0.f, 0.f, 0.f, 0.f);
          if (act && 8 + ei < cnta) f1 = *(const float4*)(Yp + s1 + q4);
          f0.x += f1.x; f0.y += f1.y; f0.z += f1.z; f0.w += f1.w;
        }
        if (cnta > 16) {
          int s2 = __shfl(esa, 16 + ei, 32);
          int s3 = __shfl(esa, 24 + ei, 32);
          float4 f2 = make_float4(0.f, 0.f, 0.f, 0.f), f3 = f2;
          if (act && 16 + ei < cnta) f2 = *(const float4*)(Yp + s2 + q4);
          if (act && 24 + ei < cnta) f3 = *(const float4*)(Yp + s3 + q4);
          f0.x += f2.x + f3.x; f0.y += f2.y + f3.y;
          f0.z += f2.z + f3.z; f0.w += f2.w + f3.w;
        }
        va0 += f0.x; va1 += f0.y; va2 += f0.z; va3 += f0.w;
      }
      if (cntb > 0) {
        int s0 = __shfl(esb, ei, 32);
        float4 f0 = make_float4(0.f, 0.f, 0.f, 0.f);
        if (act && ei < cntb) f0 = *(const float4*)(Yp + s0 + q4);
        if (cntb > 8) {
          int s1 = __shfl(esb, 8 + ei, 32);
          float4 f1 = make_float4(0.f, 0.f, 0.f, 0.f);
          if (act && 8 + ei < cntb) f1 = *(const float4*)(Yp + s1 + q4);
          f0.x += f1.x; f0.y += f1.y; f0.z += f1.z; f0.w += f1.w;
        }
        if (cntb > 16) {
          int s2 = __shfl(esb, 16 + ei, 32);
          int s3 = __shfl(esb, 24 + ei, 32);
          float4 f2 = make_float4(0.f, 0.f, 0.f, 0.f), f3 = f2;
          if (act && 16 + ei < cntb) f2 = *(const float4*)(Yp + s2 + q4);
          if (act && 24 + ei < cntb) f3 = *(const float4*)(Yp + s3 + q4);
          f0.x += f2.x + f3.x; f0.y += f2.y + f3.y;
          f0.z += f2.z + f3.z; f0.w += f2.w + f3.w;
        }
        vb0 += f0.x; vb1 += f0.y; vb2 += f0.z; vb3 += f0.w;
      }
      basea += 32; baseb += 32;
    }

    // reduce across the 8 edge slots (lanes 3k+q -> lanes 0..2)
    va0 += __shfl(va0, l + 12, 32); va1 += __shfl(va1, l + 12, 32);
    va2 += __shfl(va2, l + 12, 32); va3 += __shfl(va3, l + 12, 32);
    va0 += __shfl(va0, l + 6, 32);  va1 += __shfl(va1, l + 6, 32);
    va2 += __shfl(va2, l + 6, 32);  va3 += __shfl(va3, l + 6, 32);
    va0 += __shfl(va0, l + 3, 32);  va1 += __shfl(va1, l + 3, 32);
    va2 += __shfl(va2, l + 3, 32);  va3 += __shfl(va3, l + 3, 32);

    vb0 += __shfl(vb0, l + 12, 32); vb1 += __shfl(vb1, l + 12, 32);
    vb2 += __shfl(vb2, l + 12, 32); vb3 += __shfl(vb3, l + 12, 32);
    vb0 += __shfl(vb0, l + 6, 32);  vb1 += __shfl(vb1, l + 6, 32);
    vb2 += __shfl(vb2, l + 6, 32);  vb3 += __shfl(vb3, l + 6, 32);
    vb0 += __shfl(vb0, l + 3, 32);  vb1 += __shfl(vb1, l + 3, 32);
    vb2 += __shfl(vb2, l + 3, 32);  vb3 += __shfl(vb3, l + 3, 32);

    if (l < 3) {
      float ni = norm_in[n], c = cw[n];
      a0 += c * fmaxf(fmaf(ni, va0, b4.x), 0.f);
      a1 += c * fmaxf(fmaf(ni, va1, b4.y), 0.f);
      a2 += c * fmaxf(fmaf(ni, va2, b4.z), 0.f);
      a3 += c * fmaxf(fmaf(ni, va3, b4.w), 0.f);
      if (hb) {
        float nib = norm_in[m], cb = cw[m];
        a0 += cb * fmaxf(fmaf(nib, vb0, b4.x), 0.f);
        a1 += cb * fmaxf(fmaf(nib, vb1, b4.y), 0.f);
        a2 += cb * fmaxf(fmaf(nib, vb2, b4.z), 0.f);
        a3 += cb * fmaxf(fmaf(nib, vb3, b4.w), 0.f);
      }
    }
  }

  if (l < 3) {
    atomicAdd(&red[4 * l + 0], a0);
    atomicAdd(&red[4 * l + 1], a1);
    atomicAdd(&red[4 * l + 2], a2);
    atomicAdd(&red[4 * l + 3], a3);
  }
  __syncthreads();
  if (tid < 12) atomicAdd(&svec[12 * panel + tid], red[tid]);
}

// hg = (svec/N) @ W2 + b2 ; out = hg @ Wr^T + br
__global__ void k_final(const float* __restrict__ svec,
                        const float* __restrict__ W2, const float* __restrict__ b2,
                        const float* __restrict__ Wr, const float* __restrict__ br,
                        float* __restrict__ out) {
  __shared__ float hg[96];
  int j = threadIdx.x;
  if (j < 96) {
    float acc = b2[j];
    const float invN = 1.0f / (float)NN;
    for (int k = 0; k < 96; ++k)
      acc = fmaf(svec[k] * invN, W2[k * 96 + j], acc);
    hg[j] = acc;
  }
  __syncthreads();
  if (j < 8) {
    float acc = br[j];
    for (int k = 0; k < 96; ++k)
      acc = fmaf(hg[k], Wr[j * 96 + k], acc);
    out[j] = acc;
  }
}

extern "C" void kernel_launch(void* const* d_in, const int* in_sizes, int n_in,
                              void* d_out, int out_size, void* d_ws, size_t ws_size,
                              hipStream_t stream) {
  const float* feats = (const float*)d_in[0];
  const int*   src   = (const int*)d_in[1];
  const int*   dst   = (const int*)d_in[2];
  const float* W1    = (const float*)d_in[3];
  const float* b1    = (const float*)d_in[4];
  const float* W2    = (const float*)d_in[5];
  const float* b2    = (const float*)d_in[6];
  const float* Wr    = (const float*)d_in[7];
  const float* br    = (const float*)d_in[8];
  float* out = (float*)d_out;

  int*   wsi      = (int*)d_ws;
  float* wsf      = (float*)d_ws;
  float* svec     = wsf + OFF_SVEC;
  int*   bcur_d   = wsi + OFF_BCURD;
  int*   bcur_s   = wsi + OFF_BCURS;
  float* norm_out = wsf + OFF_NORM_OUT;
  float* norm_in  = wsf + OFF_NORM_IN;
  float* cw       = wsf + OFF_CW;
  int*   row_ptr  = wsi + OFF_ROW_PTR;
  unsigned short* edge_src = (unsigned short*)(wsi + OFF_EDGE_SRC);
  int*   pd       = wsi + OFF_PD;
  int*   ps       = wsi + OFF_PS;
  float* YP       = wsf + OFF_YP;        // aliases pd+ps (both dead by k_xform)

  hipMemsetAsync(d_ws, 0, ZERO_BYTES, stream);   // svec + padded cursors

  void* pre_args[] = {(void*)&src, (void*)&dst, (void*)&bcur_d, (void*)&bcur_s,
                      (void*)&pd, (void*)&ps, (void*)&row_ptr, (void*)&norm_in,
                      (void*)&edge_src, (void*)&norm_out, (void*)&cw};
  hipLaunchCooperativeKernel((const void*)k_pre, dim3(GRID_PRE), dim3(256),
                             pre_args, 0, stream);

  k_xform<<<(NN + 63) / 64, 256, 0, stream>>>(feats, norm_out, W1, YP);
  k_agg<<<2048, 256, 0, stream>>>(YP, norm_in, cw, row_ptr, edge_src, b1, svec);
  k_final<<<1, 128, 0, stream>>>(svec, W2, b2, Wr, br, out);
}

// Round 16
// 232.395 us; speedup vs baseline: 1.3807x; 1.3807x over previous
//
#include <hip/hip_runtime.h>

// GCN 2-layer + mean-pool + readout.
// Algebra: aggregation is linear, so transform FIRST:
//   Y      = (norm_out ⊙ X) @ W1            (dense register-tiled GEMM, fp32)
//   h1[n]  = relu( norm_in[n] * sum_{e:dst=n} Y[src_e] + b1 )
//   out    = ((1/N) * sum_u c[u]*h1[u]) @ W2 + b2  @ Wr^T + br
//   c[u]   = norm_out[u] * sum_{e:src=u} norm_in[dst_e]
//
// k_agg roofline (r9-r13): gathered volume 800K edges x 96 cols x 4B = 307MB
// = 19.2M 16B-sectors, invariant across geometries; L2 serves ~16.8
// sectors/cy/XCD -> ~60us wall. fp16 ruled out by accuracy. PARKED.
// r15 lesson: cooperative grid.sync fusion collapses occupancy (17%) and
// costs 3x — preproc stays as separate small kernels.
//
// Round-16 change: k_final fused into k_agg via last-block ticket (device-
// scope atomic + threadfence): one fewer dispatch, readout runs L2-hot.
//
// Pipeline: memset(26KB) -> k_part -> k_hist -> k_place_bin -> k_xform ->
//           k_agg(+readout) .   (6 dispatches)

constexpr int NN = 50000;
constexpr int NE = 800000;
constexpr int NB = 196;         // buckets of 256 nodes
constexpr int CAP = 6144;       // bucket capacity (mean 4082, +32 sigma)

// ws layout in 4-byte units:
constexpr int OFF_SVEC     = 0;        // float[96]   (zeroed)
constexpr int OFF_TICKET   = 128;      // int[1]      (zeroed)
constexpr int OFF_BCURD    = 256;      // int[196*16] line-padded (zeroed)
constexpr int OFF_BCURS    = 3392;     // int[196*16] line-padded (zeroed)
constexpr int OFF_NORM_OUT = 6528;     // float[50000]
constexpr int OFF_NORM_IN  = 56528;    // float[50000]
constexpr int OFF_CW       = 106528;   // float[50000]
constexpr int OFF_ROW_PTR  = 156528;   // int[50001] -> pad 206532
constexpr int OFF_EDGE_SRC = 206532;   // ushort[800000] = 400000 ints -> 606532
constexpr int OFF_PD       = 606532;   // int[196*6144] (dead after k_place_bin)
constexpr int OFF_PS       = 1810756;  // int[196*6144] (dead after k_place_bin)
constexpr int OFF_YP       = 606532;   // float[8][50000][12] aliases PD+PS
                                       // end 5406532 words = 21.6MB
constexpr size_t ZERO_BYTES = (size_t)(OFF_NORM_OUT) * 4;   // svec+ticket+cursors

// Dual partition with LDS reorder-then-flush (coalesced bucket-run writes).
__global__ __launch_bounds__(256)
void k_part(const int* __restrict__ src, const int* __restrict__ dst,
            int* __restrict__ bcur_d, int* __restrict__ bcur_s,
            int* __restrict__ pd, int* __restrict__ ps) {
  __shared__ int hd[256], hs[256], gd[256], gs[256];
  __shared__ int ldx[256], cur[256], scn[256];
  __shared__ int stage[2048];
  __shared__ unsigned char stageB[2048];
  const int t = threadIdx.x;
  hd[t] = 0; hs[t] = 0;
  __syncthreads();
  const int e0 = blockIdx.x * 2048;
  int s_[8], d_[8];
#pragma unroll
  for (int i = 0; i < 8; ++i) {
    int e = e0 + i * 256 + t;
    bool v = e < NE;
    s_[i] = v ? src[e] : -1;
    d_[i] = v ? dst[e] : -1;
    if (v) { atomicAdd(&hd[d_[i] >> 8], 1); atomicAdd(&hs[s_[i] >> 8], 1); }
  }
  __syncthreads();
  if (t < NB) {
    int c = hd[t];
    gd[t] = c ? (t * CAP + atomicAdd(&bcur_d[t * 16], c)) : 0;
    c = hs[t];
    gs[t] = c ? (t * CAP + atomicAdd(&bcur_s[t * 16], c)) : 0;
  }

  // ---- dst partition: scan -> LDS place -> linear flush ----
  scn[t] = hd[t];
  __syncthreads();
  for (int off = 1; off < 256; off <<= 1) {
    int u = (t >= off) ? scn[t - off] : 0;
    __syncthreads();
    scn[t] += u;
    __syncthreads();
  }
  ldx[t] = scn[t] - hd[t];
  cur[t] = scn[t] - hd[t];
  const int totd = scn[255];
  __syncthreads();
#pragma unroll
  for (int i = 0; i < 8; ++i) {
    if (d_[i] >= 0) {
      int B = d_[i] >> 8;
      int p = atomicAdd(&cur[B], 1);             // LDS
      stage[p] = (s_[i] << 8) | (d_[i] & 255);
      stageB[p] = (unsigned char)B;
    }
  }
  __syncthreads();
  for (int j = t; j < totd; j += 256) {          // coalesced within runs
    int B = stageB[j];
    pd[gd[B] + (j - ldx[B])] = stage[j];
  }
  __syncthreads();

  // ---- src partition: same machinery, reusing stage ----
  scn[t] = hs[t];
  __syncthreads();
  for (int off = 1; off < 256; off <<= 1) {
    int u = (t >= off) ? scn[t - off] : 0;
    __syncthreads();
    scn[t] += u;
    __syncthreads();
  }
  ldx[t] = scn[t] - hs[t];
  cur[t] = scn[t] - hs[t];
  const int tots = scn[255];
  __syncthreads();
#pragma unroll
  for (int i = 0; i < 8; ++i) {
    if (s_[i] >= 0) {
      int B = s_[i] >> 8;
      int p = atomicAdd(&cur[B], 1);             // LDS
      stage[p] = (d_[i] << 8) | (s_[i] & 255);
      stageB[p] = (unsigned char)B;
    }
  }
  __syncthreads();
  for (int j = t; j < tots; j += 256) {
    int B = stageB[j];
    ps[gs[B] + (j - ldx[B])] = stage[j];
  }
}

// Per-bucket in-degree hist -> base reduce -> 256-scan -> row_ptr + norm_in.
__global__ __launch_bounds__(256)
void k_hist(const int* __restrict__ pd, const int* __restrict__ bcur_d,
            int* __restrict__ row_ptr, float* __restrict__ norm_in) {
  __shared__ int hist[256], sc[256];
  const int t = threadIdx.x, b = blockIdx.x;
  hist[t] = 0;
  __syncthreads();
  const int cnt = bcur_d[b * 16];
  const int* pe = pd + b * CAP;
  for (int i = t; i < cnt; i += 256) atomicAdd(&hist[pe[i] & 255], 1);

  sc[t] = (t < b) ? bcur_d[t * 16] : 0;          // bucket base reduce
  __syncthreads();
  for (int s = 128; s > 0; s >>= 1) {
    if (t < s) sc[t] += sc[t + s];
    __syncthreads();
  }
  const int base0 = sc[0];
  __syncthreads();

  int h = hist[t];
  sc[t] = h;
  __syncthreads();
  for (int off = 1; off < 256; off <<= 1) {
    int u = (t >= off) ? sc[t - off] : 0;
    __syncthreads();
    sc[t] += u;
    __syncthreads();
  }
  int excl = base0 + sc[t] - h;
  int n = b * 256 + t;
  if (n < NN) {
    row_ptr[n] = excl;
    norm_in[n] = 1.0f / sqrtf((float)max(h, 1));
  }
  if (b == NB - 1 && t == 0) row_ptr[NN] = base0 + cnt;
}

// Fused placement ∥ bin_src (392 blocks): blocks 0..195 place bucket b's
// edges into CSR (cursors seeded from row_ptr); blocks 196..391 do the
// out-degree + c_raw accumulation for bucket b-196. Concurrent halves.
__global__ __launch_bounds__(256)
void k_place_bin(const int* __restrict__ pd, const int* __restrict__ ps,
                 const int* __restrict__ bcur_d, const int* __restrict__ bcur_s,
                 const int* __restrict__ row_ptr, const float* __restrict__ norm_in,
                 unsigned short* __restrict__ edge_src,
                 float* __restrict__ norm_out, float* __restrict__ cw) {
  __shared__ int ibuf[256];
  __shared__ float fbuf[256];
  const int t = threadIdx.x, bb = blockIdx.x;
  if (bb < NB) {
    // ---- placement half ----
    const int b = bb;
    int n = b * 256 + t;
    ibuf[t] = (n < NN) ? row_ptr[n] : 0;         // per-node cursor
    __syncthreads();
    const int cnt = bcur_d[b * 16];
    const int* pe = pd + b * CAP;
    for (int i = t; i < cnt; i += 256) {
      int p = pe[i];
      int pos = atomicAdd(&ibuf[p & 255], 1);    // LDS
      edge_src[pos] = (unsigned short)(p >> 8);
    }
  } else {
    // ---- bin_src half ----
    const int b = bb - NB;
    ibuf[t] = 0; fbuf[t] = 0.f;
    __syncthreads();
    const int cnt = bcur_s[b * 16];
    const int* pe = ps + b * CAP;
    for (int i = t; i < cnt; i += 256) {
      int p = pe[i];
      atomicAdd(&ibuf[p & 255], 1);              // LDS
      atomicAdd(&fbuf[p & 255], norm_in[p >> 8]);// LDS float add
    }
    __syncthreads();
    int n = b * 256 + t;
    if (n < NN) {
      float no = 1.0f / sqrtf((float)max(ibuf[t], 1));
      norm_out[n] = no;
      cw[n] = no * fbuf[t];
    }
  }
}

// Y = (norm_out ⊙ X) @ W1 — register-tiled GEMM, 8x12-col panel output.
// W1 staged in LDS in 32-row chunks (12.3KB): W1 (36.9KB) > L1 (32KB) was
// thrashing ~940MB through L2. FMA order unchanged -> bitwise-same Y.
__global__ __launch_bounds__(256, 4)
void k_xform(const float* __restrict__ feats, const float* __restrict__ norm_out,
             const float* __restrict__ W1, float* __restrict__ YP) {
  __shared__ float XT[96][68];            // [k][node], pad 64->68 (26.1KB)
  __shared__ float W1c[32][96];           // one 32-row chunk of W1 (12.3KB)
  const int t = threadIdx.x;
  const int nb = blockIdx.x * 64;         // tile base node

  const float4* f4 = (const float4*)feats;
#pragma unroll
  for (int i = 0; i < 6; ++i) {           // 6*256 = 1536 float4 = 64x96 floats
    int idx4 = i * 256 + t;
    int n = idx4 / 24;
    int kq = idx4 % 24;
    int ng = nb + n;
    float4 v = make_float4(0.f, 0.f, 0.f, 0.f);
    float no = 0.f;
    if (ng < NN) { v = f4[(size_t)ng * 24 + kq]; no = norm_out[ng]; }
    XT[kq * 4 + 0][n] = v.x * no;
    XT[kq * 4 + 1][n] = v.y * no;
    XT[kq * 4 + 2][n] = v.z * no;
    XT[kq * 4 + 3][n] = v.w * no;
  }
  __syncthreads();

  const int tn = t & 7;                   // panel / column chunk: cols 12*tn..
  const int tm = t >> 3;                  // node pair: nodes 2*tm, 2*tm+1
  float acc0[12], acc1[12];
#pragma unroll
  for (int c = 0; c < 12; ++c) { acc0[c] = 0.f; acc1[c] = 0.f; }

  for (int kb = 0; kb < 3; ++kb) {
    const float4* Wg = (const float4*)(W1 + kb * 32 * 96);
#pragma unroll
    for (int i = 0; i < 3; ++i) {
      int j = i * 256 + t;
      *(float4*)&W1c[j / 24][(j % 24) * 4] = Wg[j];
    }
    __syncthreads();
#pragma unroll
    for (int kk = 0; kk < 32; ++kk) {
      int k = kb * 32 + kk;
      float2 x = *(const float2*)&XT[k][2 * tm];
      float4 w0 = *(const float4*)&W1c[kk][12 * tn];
      float4 w1 = *(const float4*)&W1c[kk][12 * tn + 4];
      float4 w2 = *(const float4*)&W1c[kk][12 * tn + 8];
      const float w[12] = {w0.x, w0.y, w0.z, w0.w, w1.x, w1.y, w1.z, w1.w,
                           w2.x, w2.y, w2.z, w2.w};
#pragma unroll
      for (int c = 0; c < 12; ++c) {
        acc0[c] = fmaf(x.x, w[c], acc0[c]);
        acc1[c] = fmaf(x.y, w[c], acc1[c]);
      }
    }
    __syncthreads();
  }

  int n0 = nb + 2 * tm;
  if (n0 < NN) {
    float4* yp = (float4*)(YP + ((size_t)tn * NN + n0) * 12);
    yp[0] = make_float4(acc0[0], acc0[1], acc0[2], acc0[3]);
    yp[1] = make_float4(acc0[4], acc0[5], acc0[6], acc0[7]);
    yp[2] = make_float4(acc0[8], acc0[9], acc0[10], acc0[11]);
  }
  if (n0 + 1 < NN) {
    float4* yp = (float4*)(YP + ((size_t)tn * NN + n0 + 1) * 12);
    yp[0] = make_float4(acc1[0], acc1[1], acc1[2], acc1[3]);
    yp[1] = make_float4(acc1[4], acc1[5], acc1[6], acc1[7]);
    yp[2] = make_float4(acc1[8], acc1[9], acc1[10], acc1[11]);
  }
}

// Panel-per-XCD CSR gather with node-pair ILP (the ~60us L2-volume wall),
// with the readout (k_final) fused via last-block ticket.
__global__ __launch_bounds__(256, 6)
void k_agg(const float* __restrict__ YP,
           const float* __restrict__ norm_in, const float* __restrict__ cw,
           const int* __restrict__ row_ptr, const unsigned short* __restrict__ edge_src,
           const float* __restrict__ b1, float* __restrict__ svec,
           int* __restrict__ ticket,
           const float* __restrict__ W2, const float* __restrict__ b2,
           const float* __restrict__ Wr, const float* __restrict__ br,
           float* __restrict__ out) {
  __shared__ float red[12];
  const int tid = threadIdx.x;
  if (tid < 12) red[tid] = 0.f;
  __syncthreads();

  const int panel = blockIdx.x & 7;
  const int bp    = blockIdx.x >> 3;
  const int g = tid >> 5, l = tid & 31;
  const int ei = l / 3;
  const int q4 = (l - 3 * ei) * 4;          // element offset of this lane's quad
  const bool act = (l < 24);

  const float* Yp = YP + (size_t)panel * NN * 12;
  float4 b4 = make_float4(0.f, 0.f, 0.f, 0.f);
  if (l < 3) b4 = ((const float4*)b1)[3 * panel + l];

  float a0 = 0.f, a1 = 0.f, a2 = 0.f, a3 = 0.f;

  const int gid = bp * 8 + g;
  for (int n = gid; n < NN; n += 4096) {
    const int m = n + 2048;
    const bool hb = (m < NN);
    int e1a = row_ptr[n + 1], basea = row_ptr[n];
    int e1b = 0, baseb = 0;
    if (hb) { e1b = row_ptr[m + 1]; baseb = row_ptr[m]; }
    float va0 = 0.f, va1 = 0.f, va2 = 0.f, va3 = 0.f;
    float vb0 = 0.f, vb1 = 0.f, vb2 = 0.f, vb3 = 0.f;

    while (basea < e1a || baseb < e1b) {
      int cnta = min(32, e1a - basea);
      int cntb = min(32, e1b - baseb);
      int esa = 0, esb = 0;
      if (basea + l < e1a) esa = edge_src[basea + l] * 12;
      if (baseb + l < e1b) esb = edge_src[baseb + l] * 12;

      if (cnta > 0) {
        int s0 = __shfl(esa, ei, 32);
        float4 f0 = make_float4(0.f, 0.f, 0.f, 0.f);
        if (act && ei < cnta) f0 = *(const float4*)(Yp + s0 + q4);
        if (cnta > 8) {
          int s1 = __shfl(esa, 8 + ei, 32);
          float4 f1 = make_float4(0.f, 0.f, 0.f, 0.f);
          if (act && 8 + ei < cnta) f1 = *(const float4*)(Yp + s1 + q4);
          f0.x += f1.x; f0.y += f1.y; f0.z += f1.z; f0.w += f1.w;
        }
        if (cnta > 16) {
          int s2 = __shfl(esa, 16 + ei, 32);
          int s3 = __shfl(esa, 24 + ei, 32);
          float4 f2 = make_float4(0.f, 0.f, 0.f, 0.f), f3 = f2;
          if (act && 16 + ei < cnta) f2 = *(const float4*)(Yp + s2 + q4);
          if (act && 24 + ei < cnta) f3 = *(const float4*)(Yp + s3 + q4);
          f0.x += f2.x + f3.x; f0.y += f2.y + f3.y;
          f0.z += f2.z + f3.z; f0.w += f2.w + f3.w;
        }
        va0 += f0.x; va1 += f0.y; va2 += f0.z; va3 += f0.w;
      }
      if (cntb > 0) {
        int s0 = __shfl(esb, ei, 32);
        float4 f0 = make_float4(0.f, 0.f, 0.f, 0.f);
        if (act && ei < cntb) f0 = *(const float4*)(Yp + s0 + q4);
        if (cntb > 8) {
          int s1 = __shfl(esb, 8 + ei, 32);
          float4 f1 = make_float4(0.f, 0.f, 0.f, 0.f);
          if (act && 8 + ei < cntb) f1 = *(const float4*)(Yp + s1 + q4);
          f0.x += f1.x; f0.y += f1.y; f0.z += f1.z; f0.w += f1.w;
        }
        if (cntb > 16) {
          int s2 = __shfl(esb, 16 + ei, 32);
          int s3 = __shfl(esb, 24 + ei, 32);
          float4 f2 = make_float4(0.f, 0.f, 0.f, 0.f), f3 = f2;
          if (act && 16 + ei < cntb) f2 = *(const float4*)(Yp + s2 + q4);
          if (act && 24 + ei < cntb) f3 = *(const float4*)(Yp + s3 + q4);
          f0.x += f2.x + f3.x; f0.y += f2.y + f3.y;
          f0.z += f2.z + f3.z; f0.w += f2.w + f3.w;
        }
        vb0 += f0.x; vb1 += f0.y; vb2 += f0.z; vb3 += f0.w;
      }
      basea += 32; baseb += 32;
    }

    // reduce across the 8 edge slots (lanes 3k+q -> lanes 0..2)
    va0 += __shfl(va0, l + 12, 32); va1 += __shfl(va1, l + 12, 32);
    va2 += __shfl(va2, l + 12, 32); va3 += __shfl(va3, l + 12, 32);
    va0 += __shfl(va0, l + 6, 32);  va1 += __shfl(va1, l + 6, 32);
    va2 += __shfl(va2, l + 6, 32);  va3 += __shfl(va3, l + 6, 32);
    va0 += __shfl(va0, l + 3, 32);  va1 += __shfl(va1, l + 3, 32);
    va2 += __shfl(va2, l + 3, 32);  va3 += __shfl(va3, l + 3, 32);

    vb0 += __shfl(vb0, l + 12, 32); vb1 += __shfl(vb1, l + 12, 32);
    vb2 += __shfl(vb2, l + 12, 32); vb3 += __shfl(vb3, l + 12, 32);
    vb0 += __shfl(vb0, l + 6, 32);  vb1 += __shfl(vb1, l + 6, 32);
    vb2 += __shfl(vb2, l + 6, 32);  vb3 += __shfl(vb3, l + 6, 32);
    vb0 += __shfl(vb0, l + 3, 32);  vb1 += __shfl(vb1, l + 3, 32);
    vb2 += __shfl(vb2, l + 3, 32);  vb3 += __shfl(vb3, l + 3, 32);

    if (l < 3) {
      float ni = norm_in[n], c = cw[n];
      a0 += c * fmaxf(fmaf(ni, va0, b4.x), 0.f);
      a1 += c * fmaxf(fmaf(ni, va1, b4.y), 0.f);
      a2 += c * fmaxf(fmaf(ni, va2, b4.z), 0.f);
      a3 += c * fmaxf(fmaf(ni, va3, b4.w), 0.f);
      if (hb) {
        float nib = norm_in[m], cb = cw[m];
        a0 += cb * fmaxf(fmaf(nib, vb0, b4.x), 0.f);
        a1 += cb * fmaxf(fmaf(nib, vb1, b4.y), 0.f);
        a2 += cb * fmaxf(fmaf(nib, vb2, b4.z), 0.f);
        a3 += cb * fmaxf(fmaf(nib, vb3, b4.w), 0.f);
      }
    }
  }

  if (l < 3) {
    atomicAdd(&red[4 * l + 0], a0);
    atomicAdd(&red[4 * l + 1], a1);
    atomicAdd(&red[4 * l + 2], a2);
    atomicAdd(&red[4 * l + 3], a3);
  }
  __syncthreads();
  if (tid < 12) atomicAdd(&svec[12 * panel + tid], red[tid]);

  // ---- fused readout: last block computes out = ((svec/N)@W2+b2)@Wr^T+br ----
  __shared__ int is_last;
  __shared__ float hg[96];
  if (tid == 0) {
    __threadfence();                              // release svec writes
    int old = atomicAdd(ticket, 1);
    is_last = (old == (int)gridDim.x - 1);
  }
  __syncthreads();
  if (!is_last) return;
  __threadfence();                                // acquire all svec writes
  if (tid < 96) {
    float acc = b2[tid];
    const float invN = 1.0f / (float)NN;
    for (int k = 0; k < 96; ++k)
      acc = fmaf(svec[k] * invN, W2[k * 96 + tid], acc);
    hg[tid] = acc;
  }
  __syncthreads();
  if (tid < 8) {
    float acc = br[tid];
    for (int k = 0; k < 96; ++k)
      acc = fmaf(hg[k], Wr[tid * 96 + k], acc);
    out[tid] = acc;
  }
}

extern "C" void kernel_launch(void* const* d_in, const int* in_sizes, int n_in,
                              void* d_out, int out_size, void* d_ws, size_t ws_size,
                              hipStream_t stream) {
  const float* feats = (const float*)d_in[0];
  const int*   src   = (const int*)d_in[1];
  const int*   dst   = (const int*)d_in[2];
  const float* W1    = (const float*)d_in[3];
  const float* b1    = (const float*)d_in[4];
  const float* W2    = (const float*)d_in[5];
  const float* b2    = (const float*)d_in[6];
  const float* Wr    = (const float*)d_in[7];
  const float* br    = (const float*)d_in[8];
  float* out = (float*)d_out;

  int*   wsi      = (int*)d_ws;
  float* wsf      = (float*)d_ws;
  float* svec     = wsf + OFF_SVEC;
  int*   ticket   = wsi + OFF_TICKET;
  int*   bcur_d   = wsi + OFF_BCURD;
  int*   bcur_s   = wsi + OFF_BCURS;
  float* norm_out = wsf + OFF_NORM_OUT;
  float* norm_in  = wsf + OFF_NORM_IN;
  float* cw       = wsf + OFF_CW;
  int*   row_ptr  = wsi + OFF_ROW_PTR;
  unsigned short* edge_src = (unsigned short*)(wsi + OFF_EDGE_SRC);
  int*   pd       = wsi + OFF_PD;
  int*   ps       = wsi + OFF_PS;
  float* YP       = wsf + OFF_YP;        // aliases pd+ps (both dead by k_xform)

  hipMemsetAsync(d_ws, 0, ZERO_BYTES, stream);   // svec + ticket + cursors

  k_part<<<(NE + 2047) / 2048, 256, 0, stream>>>(src, dst, bcur_d, bcur_s, pd, ps);
  k_hist<<<NB, 256, 0, stream>>>(pd, bcur_d, row_ptr, norm_in);
  k_place_bin<<<2 * NB, 256, 0, stream>>>(pd, ps, bcur_d, bcur_s, row_ptr,
                                          norm_in, edge_src, norm_out, cw);
  k_xform<<<(NN + 63) / 64, 256, 0, stream>>>(feats, norm_out, W1, YP);
  k_agg<<<2048, 256, 0, stream>>>(YP, norm_in, cw, row_ptr, edge_src, b1, svec,
                                  ticket, W2, b2, Wr, br, out);
}

// Round 17
// 204.182 us; speedup vs baseline: 1.5715x; 1.1382x over previous
//
#include <hip/hip_runtime.h>

// GCN 2-layer + mean-pool + readout.
// Algebra: aggregation is linear, so transform FIRST:
//   Y      = (norm_out ⊙ X) @ W1            (dense register-tiled GEMM, fp32)
//   h1[n]  = relu( norm_in[n] * sum_{e:dst=n} Y[src_e] + b1 )
//   out    = ((1/N) * sum_u c[u]*h1[u]) @ W2 + b2  @ Wr^T + br
//   c[u]   = norm_out[u] * sum_{e:src=u} norm_in[dst_e]
//
// k_agg roofline (r9-r13): gathered volume 800K edges x 96 cols x 4B = 307MB
// = 19.2M 16B-sectors, invariant across geometries; L2 serves ~16.8
// sectors/cy/XCD -> ~60us wall. fp16 ruled out by accuracy. PARKED.
// r15: coop grid.sync fusion = 3x worse (occupancy collapse). r16: ticket+
// threadfence readout fusion = +34us (device-scope fence per block drains
// writes at the coherence point). Separate small kernels are optimal here.
//
// Pipeline: memset(26KB) -> k_part -> k_hist -> k_place_bin -> k_xform ->
//           k_agg -> k_final.   (7 dispatches; round-14 best-verified state)

constexpr int NN = 50000;
constexpr int NE = 800000;
constexpr int NB = 196;         // buckets of 256 nodes
constexpr int CAP = 6144;       // bucket capacity (mean 4082, +32 sigma)

// ws layout in 4-byte units:
constexpr int OFF_SVEC     = 0;        // float[256]  (zeroed)
constexpr int OFF_BCURD    = 256;      // int[196*16] line-padded (zeroed)
constexpr int OFF_BCURS    = 3392;     // int[196*16] line-padded (zeroed)
constexpr int OFF_NORM_OUT = 6528;     // float[50000]
constexpr int OFF_NORM_IN  = 56528;    // float[50000]
constexpr int OFF_CW       = 106528;   // float[50000]
constexpr int OFF_ROW_PTR  = 156528;   // int[50001] -> pad 206532
constexpr int OFF_EDGE_SRC = 206532;   // ushort[800000] = 400000 ints -> 606532
constexpr int OFF_PD       = 606532;   // int[196*6144] (dead after k_place_bin)
constexpr int OFF_PS       = 1810756;  // int[196*6144] (dead after k_place_bin)
constexpr int OFF_YP       = 606532;   // float[8][50000][12] aliases PD+PS
                                       // end 5406532 words = 21.6MB
constexpr size_t ZERO_BYTES = (size_t)(OFF_NORM_OUT) * 4;   // svec + cursors

// Dual partition with LDS reorder-then-flush (coalesced bucket-run writes).
__global__ __launch_bounds__(256)
void k_part(const int* __restrict__ src, const int* __restrict__ dst,
            int* __restrict__ bcur_d, int* __restrict__ bcur_s,
            int* __restrict__ pd, int* __restrict__ ps) {
  __shared__ int hd[256], hs[256], gd[256], gs[256];
  __shared__ int ldx[256], cur[256], scn[256];
  __shared__ int stage[2048];
  __shared__ unsigned char stageB[2048];
  const int t = threadIdx.x;
  hd[t] = 0; hs[t] = 0;
  __syncthreads();
  const int e0 = blockIdx.x * 2048;
  int s_[8], d_[8];
#pragma unroll
  for (int i = 0; i < 8; ++i) {
    int e = e0 + i * 256 + t;
    bool v = e < NE;
    s_[i] = v ? src[e] : -1;
    d_[i] = v ? dst[e] : -1;
    if (v) { atomicAdd(&hd[d_[i] >> 8], 1); atomicAdd(&hs[s_[i] >> 8], 1); }
  }
  __syncthreads();
  if (t < NB) {
    int c = hd[t];
    gd[t] = c ? (t * CAP + atomicAdd(&bcur_d[t * 16], c)) : 0;
    c = hs[t];
    gs[t] = c ? (t * CAP + atomicAdd(&bcur_s[t * 16], c)) : 0;
  }

  // ---- dst partition: scan -> LDS place -> linear flush ----
  scn[t] = hd[t];
  __syncthreads();
  for (int off = 1; off < 256; off <<= 1) {
    int u = (t >= off) ? scn[t - off] : 0;
    __syncthreads();
    scn[t] += u;
    __syncthreads();
  }
  ldx[t] = scn[t] - hd[t];
  cur[t] = scn[t] - hd[t];
  const int totd = scn[255];
  __syncthreads();
#pragma unroll
  for (int i = 0; i < 8; ++i) {
    if (d_[i] >= 0) {
      int B = d_[i] >> 8;
      int p = atomicAdd(&cur[B], 1);             // LDS
      stage[p] = (s_[i] << 8) | (d_[i] & 255);
      stageB[p] = (unsigned char)B;
    }
  }
  __syncthreads();
  for (int j = t; j < totd; j += 256) {          // coalesced within runs
    int B = stageB[j];
    pd[gd[B] + (j - ldx[B])] = stage[j];
  }
  __syncthreads();

  // ---- src partition: same machinery, reusing stage ----
  scn[t] = hs[t];
  __syncthreads();
  for (int off = 1; off < 256; off <<= 1) {
    int u = (t >= off) ? scn[t - off] : 0;
    __syncthreads();
    scn[t] += u;
    __syncthreads();
  }
  ldx[t] = scn[t] - hs[t];
  cur[t] = scn[t] - hs[t];
  const int tots = scn[255];
  __syncthreads();
#pragma unroll
  for (int i = 0; i < 8; ++i) {
    if (s_[i] >= 0) {
      int B = s_[i] >> 8;
      int p = atomicAdd(&cur[B], 1);             // LDS
      stage[p] = (d_[i] << 8) | (s_[i] & 255);
      stageB[p] = (unsigned char)B;
    }
  }
  __syncthreads();
  for (int j = t; j < tots; j += 256) {
    int B = stageB[j];
    ps[gs[B] + (j - ldx[B])] = stage[j];
  }
}

// Per-bucket in-degree hist -> base reduce -> 256-scan -> row_ptr + norm_in.
__global__ __launch_bounds__(256)
void k_hist(const int* __restrict__ pd, const int* __restrict__ bcur_d,
            int* __restrict__ row_ptr, float* __restrict__ norm_in) {
  __shared__ int hist[256], sc[256];
  const int t = threadIdx.x, b = blockIdx.x;
  hist[t] = 0;
  __syncthreads();
  const int cnt = bcur_d[b * 16];
  const int* pe = pd + b * CAP;
  for (int i = t; i < cnt; i += 256) atomicAdd(&hist[pe[i] & 255], 1);

  sc[t] = (t < b) ? bcur_d[t * 16] : 0;          // bucket base reduce
  __syncthreads();
  for (int s = 128; s > 0; s >>= 1) {
    if (t < s) sc[t] += sc[t + s];
    __syncthreads();
  }
  const int base0 = sc[0];
  __syncthreads();

  int h = hist[t];
  sc[t] = h;
  __syncthreads();
  for (int off = 1; off < 256; off <<= 1) {
    int u = (t >= off) ? sc[t - off] : 0;
    __syncthreads();
    sc[t] += u;
    __syncthreads();
  }
  int excl = base0 + sc[t] - h;
  int n = b * 256 + t;
  if (n < NN) {
    row_ptr[n] = excl;
    norm_in[n] = 1.0f / sqrtf((float)max(h, 1));
  }
  if (b == NB - 1 && t == 0) row_ptr[NN] = base0 + cnt;
}

// Fused placement ∥ bin_src (392 blocks): blocks 0..195 place bucket b's
// edges into CSR (cursors seeded from row_ptr); blocks 196..391 do the
// out-degree + c_raw accumulation for bucket b-196. Concurrent halves.
__global__ __launch_bounds__(256)
void k_place_bin(const int* __restrict__ pd, const int* __restrict__ ps,
                 const int* __restrict__ bcur_d, const int* __restrict__ bcur_s,
                 const int* __restrict__ row_ptr, const float* __restrict__ norm_in,
                 unsigned short* __restrict__ edge_src,
                 float* __restrict__ norm_out, float* __restrict__ cw) {
  __shared__ int ibuf[256];
  __shared__ float fbuf[256];
  const int t = threadIdx.x, bb = blockIdx.x;
  if (bb < NB) {
    // ---- placement half ----
    const int b = bb;
    int n = b * 256 + t;
    ibuf[t] = (n < NN) ? row_ptr[n] : 0;         // per-node cursor
    __syncthreads();
    const int cnt = bcur_d[b * 16];
    const int* pe = pd + b * CAP;
    for (int i = t; i < cnt; i += 256) {
      int p = pe[i];
      int pos = atomicAdd(&ibuf[p & 255], 1);    // LDS
      edge_src[pos] = (unsigned short)(p >> 8);
    }
  } else {
    // ---- bin_src half ----
    const int b = bb - NB;
    ibuf[t] = 0; fbuf[t] = 0.f;
    __syncthreads();
    const int cnt = bcur_s[b * 16];
    const int* pe = ps + b * CAP;
    for (int i = t; i < cnt; i += 256) {
      int p = pe[i];
      atomicAdd(&ibuf[p & 255], 1);              // LDS
      atomicAdd(&fbuf[p & 255], norm_in[p >> 8]);// LDS float add
    }
    __syncthreads();
    int n = b * 256 + t;
    if (n < NN) {
      float no = 1.0f / sqrtf((float)max(ibuf[t], 1));
      norm_out[n] = no;
      cw[n] = no * fbuf[t];
    }
  }
}

// Y = (norm_out ⊙ X) @ W1 — register-tiled GEMM, 8x12-col panel output.
// W1 staged in LDS in 32-row chunks (12.3KB): W1 (36.9KB) > L1 (32KB) was
// thrashing ~940MB through L2. FMA order unchanged -> bitwise-same Y.
__global__ __launch_bounds__(256, 4)
void k_xform(const float* __restrict__ feats, const float* __restrict__ norm_out,
             const float* __restrict__ W1, float* __restrict__ YP) {
  __shared__ float XT[96][68];            // [k][node], pad 64->68 (26.1KB)
  __shared__ float W1c[32][96];           // one 32-row chunk of W1 (12.3KB)
  const int t = threadIdx.x;
  const int nb = blockIdx.x * 64;         // tile base node

  const float4* f4 = (const float4*)feats;
#pragma unroll
  for (int i = 0; i < 6; ++i) {           // 6*256 = 1536 float4 = 64x96 floats
    int idx4 = i * 256 + t;
    int n = idx4 / 24;
    int kq = idx4 % 24;
    int ng = nb + n;
    float4 v = make_float4(0.f, 0.f, 0.f, 0.f);
    float no = 0.f;
    if (ng < NN) { v = f4[(size_t)ng * 24 + kq]; no = norm_out[ng]; }
    XT[kq * 4 + 0][n] = v.x * no;
    XT[kq * 4 + 1][n] = v.y * no;
    XT[kq * 4 + 2][n] = v.z * no;
    XT[kq * 4 + 3][n] = v.w * no;
  }
  __syncthreads();

  const int tn = t & 7;                   // panel / column chunk: cols 12*tn..
  const int tm = t >> 3;                  // node pair: nodes 2*tm, 2*tm+1
  float acc0[12], acc1[12];
#pragma unroll
  for (int c = 0; c < 12; ++c) { acc0[c] = 0.f; acc1[c] = 0.f; }

  for (int kb = 0; kb < 3; ++kb) {
    const float4* Wg = (const float4*)(W1 + kb * 32 * 96);
#pragma unroll
    for (int i = 0; i < 3; ++i) {
      int j = i * 256 + t;
      *(float4*)&W1c[j / 24][(j % 24) * 4] = Wg[j];
    }
    __syncthreads();
#pragma unroll
    for (int kk = 0; kk < 32; ++kk) {
      int k = kb * 32 + kk;
      float2 x = *(const float2*)&XT[k][2 * tm];
      float4 w0 = *(const float4*)&W1c[kk][12 * tn];
      float4 w1 = *(const float4*)&W1c[kk][12 * tn + 4];
      float4 w2 = *(const float4*)&W1c[kk][12 * tn + 8];
      const float w[12] = {w0.x, w0.y, w0.z, w0.w, w1.x, w1.y, w1.z, w1.w,
                           w2.x, w2.y, w2.z, w2.w};
#pragma unroll
      for (int c = 0; c < 12; ++c) {
        acc0[c] = fmaf(x.x, w[c], acc0[c]);
        acc1[c] = fmaf(x.y, w[c], acc1[c]);
      }
    }
    __syncthreads();
  }

  int n0 = nb + 2 * tm;
  if (n0 < NN) {
    float4* yp = (float4*)(YP + ((size_t)tn * NN + n0) * 12);
    yp[0] = make_float4(acc0[0], acc0[1], acc0[2], acc0[3]);
    yp[1] = make_float4(acc0[4], acc0[5], acc0[6], acc0[7]);
    yp[2] = make_float4(acc0[8], acc0[9], acc0[10], acc0[11]);
  }
  if (n0 + 1 < NN) {
    float4* yp = (float4*)(YP + ((size_t)tn * NN + n0 + 1) * 12);
    yp[0] = make_float4(acc1[0], acc1[1], acc1[2], acc1[3]);
    yp[1] = make_float4(acc1[4], acc1[5], acc1[6], acc1[7]);
    yp[2] = make_float4(acc1[8], acc1[9], acc1[10], acc1[11]);
  }
}

// Panel-per-XCD CSR gather with node-pair ILP (the ~60us L2-volume wall).
__global__ __launch_bounds__(256, 6)
void k_agg(const float* __restrict__ YP,
           const float* __restrict__ norm_in, const float* __restrict__ cw,
           const int* __restrict__ row_ptr, const unsigned short* __restrict__ edge_src,
           const float* __restrict__ b1, float* __restrict__ svec) {
  __shared__ float red[12];
  const int tid = threadIdx.x;
  if (tid < 12) red[tid] = 0.f;
  __syncthreads();

  const int panel = blockIdx.x & 7;
  const int bp    = blockIdx.x >> 3;
  const int g = tid >> 5, l = tid & 31;
  const int ei = l / 3;
  const int q4 = (l - 3 * ei) * 4;          // element offset of this lane's quad
  const bool act = (l < 24);

  const float* Yp = YP + (size_t)panel * NN * 12;
  float4 b4 = make_float4(0.f, 0.f, 0.f, 0.f);
  if (l < 3) b4 = ((const float4*)b1)[3 * panel + l];

  float a0 = 0.f, a1 = 0.f, a2 = 0.f, a3 = 0.f;

  const int gid = bp * 8 + g;
  for (int n = gid; n < NN; n += 4096) {
    const int m = n + 2048;
    const bool hb = (m < NN);
    int e1a = row_ptr[n + 1], basea = row_ptr[n];
    int e1b = 0, baseb = 0;
    if (hb) { e1b = row_ptr[m + 1]; baseb = row_ptr[m]; }
    float va0 = 0.f, va1 = 0.f, va2 = 0.f, va3 = 0.f;
    float vb0 = 0.f, vb1 = 0.f, vb2 = 0.f, vb3 = 0.f;

    while (basea < e1a || baseb < e1b) {
      int cnta = min(32, e1a - basea);
      int cntb = min(32, e1b - baseb);
      int esa = 0, esb = 0;
      if (basea + l < e1a) esa = edge_src[basea + l] * 12;
      if (baseb + l < e1b) esb = edge_src[baseb + l] * 12;

      if (cnta > 0) {
        int s0 = __shfl(esa, ei, 32);
        float4 f0 = make_float4(0.f, 0.f, 0.f, 0.f);
        if (act && ei < cnta) f0 = *(const float4*)(Yp + s0 + q4);
        if (cnta > 8) {
          int s1 = __shfl(esa, 8 + ei, 32);
          float4 f1 = make_float4(0.f, 0.f, 0.f, 0.f);
          if (act && 8 + ei < cnta) f1 = *(const float4*)(Yp + s1 + q4);
          f0.x += f1.x; f0.y += f1.y; f0.z += f1.z; f0.w += f1.w;
        }
        if (cnta > 16) {
          int s2 = __shfl(esa, 16 + ei, 32);
          int s3 = __shfl(esa, 24 + ei, 32);
          float4 f2 = make_float4(0.f, 0.f, 0.f, 0.f), f3 = f2;
          if (act && 16 + ei < cnta) f2 = *(const float4*)(Yp + s2 + q4);
          if (act && 24 + ei < cnta) f3 = *(const float4*)(Yp + s3 + q4);
          f0.x += f2.x + f3.x; f0.y += f2.y + f3.y;
          f0.z += f2.z + f3.z; f0.w += f2.w + f3.w;
        }
        va0 += f0.x; va1 += f0.y; va2 += f0.z; va3 += f0.w;
      }
      if (cntb > 0) {
        int s0 = __shfl(esb, ei, 32);
        float4 f0 = make_float4(0.f, 0.f, 0.f, 0.f);
        if (act && ei < cntb) f0 = *(const float4*)(Yp + s0 + q4);
        if (cntb > 8) {
          int s1 = __shfl(esb, 8 + ei, 32);
          float4 f1 = make_float4(0.f, 0.f, 0.f, 0.f);
          if (act && 8 + ei < cntb) f1 = *(const float4*)(Yp + s1 + q4);
          f0.x += f1.x; f0.y += f1.y; f0.z += f1.z; f0.w += f1.w;
        }
        if (cntb > 16) {
          int s2 = __shfl(esb, 16 + ei, 32);
          int s3 = __shfl(esb, 24 + ei, 32);
          float4 f2 = make_float4(0.f, 0.f, 0.f, 0.f), f3 = f2;
          if (act && 16 + ei < cntb) f2 = *(const float4*)(Yp + s2 + q4);
          if (act && 24 + ei < cntb) f3 = *(const float4*)(Yp + s3 + q4);
          f0.x += f2.x + f3.x; f0.y += f2.y + f3.y;
          f0.z += f2.z + f3.z; f0.w += f2.w + f3.w;
        }
        vb0 += f0.x; vb1 += f0.y; vb2 += f0.z; vb3 += f0.w;
      }
      basea += 32; baseb += 32;
    }

    // reduce across the 8 edge slots (lanes 3k+q -> lanes 0..2)
    va0 += __shfl(va0, l + 12, 32); va1 += __shfl(va1, l + 12, 32);
    va2 += __shfl(va2, l + 12, 32); va3 += __shfl(va3, l + 12, 32);
    va0 += __shfl(va0, l + 6, 32);  va1 += __shfl(va1, l + 6, 32);
    va2 += __shfl(va2, l + 6, 32);  va3 += __shfl(va3, l + 6, 32);
    va0 += __shfl(va0, l + 3, 32);  va1 += __shfl(va1, l + 3, 32);
    va2 += __shfl(va2, l + 3, 32);  va3 += __shfl(va3, l + 3, 32);

    vb0 += __shfl(vb0, l + 12, 32); vb1 += __shfl(vb1, l + 12, 32);
    vb2 += __shfl(vb2, l + 12, 32); vb3 += __shfl(vb3, l + 12, 32);
    vb0 += __shfl(vb0, l + 6, 32);  vb1 += __shfl(vb1, l + 6, 32);
    vb2 += __shfl(vb2, l + 6, 32);  vb3 += __shfl(vb3, l + 6, 32);
    vb0 += __shfl(vb0, l + 3, 32);  vb1 += __shfl(vb1, l + 3, 32);
    vb2 += __shfl(vb2, l + 3, 32);  vb3 += __shfl(vb3, l + 3, 32);

    if (l < 3) {
      float ni = norm_in[n], c = cw[n];
      a0 += c * fmaxf(fmaf(ni, va0, b4.x), 0.f);
      a1 += c * fmaxf(fmaf(ni, va1, b4.y), 0.f);
      a2 += c * fmaxf(fmaf(ni, va2, b4.z), 0.f);
      a3 += c * fmaxf(fmaf(ni, va3, b4.w), 0.f);
      if (hb) {
        float nib = norm_in[m], cb = cw[m];
        a0 += cb * fmaxf(fmaf(nib, vb0, b4.x), 0.f);
        a1 += cb * fmaxf(fmaf(nib, vb1, b4.y), 0.f);
        a2 += cb * fmaxf(fmaf(nib, vb2, b4.z), 0.f);
        a3 += cb * fmaxf(fmaf(nib, vb3, b4.w), 0.f);
      }
    }
  }

  if (l < 3) {
    atomicAdd(&red[4 * l + 0], a0);
    atomicAdd(&red[4 * l + 1], a1);
    atomicAdd(&red[4 * l + 2], a2);
    atomicAdd(&red[4 * l + 3], a3);
  }
  __syncthreads();
  if (tid < 12) atomicAdd(&svec[12 * panel + tid], red[tid]);
}

// hg = (svec/N) @ W2 + b2 ; out = hg @ Wr^T + br
__global__ void k_final(const float* __restrict__ svec,
                        const float* __restrict__ W2, const float* __restrict__ b2,
                        const float* __restrict__ Wr, const float* __restrict__ br,
                        float* __restrict__ out) {
  __shared__ float hg[96];
  int j = threadIdx.x;
  if (j < 96) {
    float acc = b2[j];
    const float invN = 1.0f / (float)NN;
    for (int k = 0; k < 96; ++k)
      acc = fmaf(svec[k] * invN, W2[k * 96 + j], acc);
    hg[j] = acc;
  }
  __syncthreads();
  if (j < 8) {
    float acc = br[j];
    for (int k = 0; k < 96; ++k)
      acc = fmaf(hg[k], Wr[j * 96 + k], acc);
    out[j] = acc;
  }
}

extern "C" void kernel_launch(void* const* d_in, const int* in_sizes, int n_in,
                              void* d_out, int out_size, void* d_ws, size_t ws_size,
                              hipStream_t stream) {
  const float* feats = (const float*)d_in[0];
  const int*   src   = (const int*)d_in[1];
  const int*   dst   = (const int*)d_in[2];
  const float* W1    = (const float*)d_in[3];
  const float* b1    = (const float*)d_in[4];
  const float* W2    = (const float*)d_in[5];
  const float* b2    = (const float*)d_in[6];
  const float* Wr    = (const float*)d_in[7];
  const float* br    = (const float*)d_in[8];
  float* out = (float*)d_out;

  int*   wsi      = (int*)d_ws;
  float* wsf      = (float*)d_ws;
  float* svec     = wsf + OFF_SVEC;
  int*   bcur_d   = wsi + OFF_BCURD;
  int*   bcur_s   = wsi + OFF_BCURS;
  float* norm_out = wsf + OFF_NORM_OUT;
  float* norm_in  = wsf + OFF_NORM_IN;
  float* cw       = wsf + OFF_CW;
  int*   row_ptr  = wsi + OFF_ROW_PTR;
  unsigned short* edge_src = (unsigned short*)(wsi + OFF_EDGE_SRC);
  int*   pd       = wsi + OFF_PD;
  int*   ps       = wsi + OFF_PS;
  float* YP       = wsf + OFF_YP;        // aliases pd+ps (both dead by k_xform)

  hipMemsetAsync(d_ws, 0, ZERO_BYTES, stream);   // svec + padded cursors

  k_part<<<(NE + 2047) / 2048, 256, 0, stream>>>(src, dst, bcur_d, bcur_s, pd, ps);
  k_hist<<<NB, 256, 0, stream>>>(pd, bcur_d, row_ptr, norm_in);
  k_place_bin<<<2 * NB, 256, 0, stream>>>(pd, ps, bcur_d, bcur_s, row_ptr,
                                          norm_in, edge_src, norm_out, cw);
  k_xform<<<(NN + 63) / 64, 256, 0, stream>>>(feats, norm_out, W1, YP);
  k_agg<<<2048, 256, 0, stream>>>(YP, norm_in, cw, row_ptr, edge_src, b1, svec);
  k_final<<<1, 128, 0, stream>>>(svec, W2, b2, Wr, br, out);
}